// Round 1
// baseline (181.401 us; speedup 1.0000x reference)
//
#include <hip/hip_runtime.h>

// YOLO loss forward, MI355X.
// Shapes: x0 (32,255,13,13), x1 (32,255,26,26), x2 (32,255,52,52), batch_y (32,20,5).
// Output: scalar fp32 sum over (b,g) of  mse - obj - noobj - ce.
//
// Key structural insight: the per-(b,g) argmax/noobj scan over all N=10647
// predictions needs only channels 0..4 of each prediction (x/y/w/h/conf).
// Class channels (80 of 85) are read only at the 20 argmax positions per batch.

constexpr int B_ = 32;
constexpr int G_ = 20;
constexpr int C_ = 80;
// n-space: scale0 (W=13): 3*169 = 507  -> base 0
//          scale1 (W=26): 3*676 = 2028 -> base 507
//          scale2 (W=52): 3*2704= 8112 -> base 2535; total 10647

__global__ void zero_out_kernel(float* __restrict__ out) {
    out[0] = 0.0f;
}

__device__ __forceinline__ float sigm(float x) { return 1.0f / (1.0f + expf(-x)); }

// Scan one scale's predictions for this (b,g) block.
// aw/ah are floor(anchor/sf)*sf, precomputed as compile-time constants.
template <int W, int NBASE>
__device__ __forceinline__ void scan_scale(
    const float* __restrict__ x, int b, float sf,
    float aw0, float aw1, float aw2, float ah0, float ah1, float ah2,
    float gxc, float gyc, float gx2, float gy2, float garea,
    float& best_iou, int& best_idx, float& neg_sum, float& neg_cnt)
{
    constexpr int WW = W * W;
    constexpr int NS = 3 * WW;
    for (int i = threadIdx.x; i < NS; i += 256) {
        int a   = i / WW;          // magic-mul (WW constexpr)
        int rem = i - a * WW;
        int y   = rem / W;
        int xi  = rem - y * W;
        const float* base = x + (size_t)(b * 255 + a * 85) * WW + rem;
        float p0 = base[0];
        float p1 = base[WW];
        float p2 = base[2 * WW];
        float p3 = base[3 * WW];
        float p4 = base[4 * WW];
        float aw = (a == 0) ? aw0 : ((a == 1) ? aw1 : aw2);
        float ah = (a == 0) ? ah0 : ((a == 1) ? ah1 : ah2);
        float px = (sigm(p0) + (float)xi) * sf;
        float py = (sigm(p1) + (float)y) * sf;
        float pw = expf(p2) * aw;
        float ph = expf(p3) * ah;
        float conf = sigm(p4);
        // Reference IoU treats (px,py) as corner: xr = px+pw etc.
        float xl = fmaxf(px, gxc);
        float yt = fmaxf(py, gyc);
        float xr = fminf(px + pw, gx2);
        float yb = fminf(py + ph, gy2);
        float inter = fmaxf(xr - xl, 0.0f) * fmaxf(yb - yt, 0.0f);
        float iou = inter / (pw * ph + garea - inter);
        if (iou > best_iou) { best_iou = iou; best_idx = NBASE + i; }  // first-max within thread (ascending n)
        if (iou < 0.5f) { neg_sum += logf(1.0f - conf + 1e-9f); neg_cnt += 1.0f; }
    }
}

__global__ __launch_bounds__(256) void yolo_loss_kernel(
    const float* __restrict__ x0, const float* __restrict__ x1,
    const float* __restrict__ x2, const float* __restrict__ by,
    float* __restrict__ out)
{
    const int g = blockIdx.x;
    const int b = blockIdx.y;
    const float* yrow = by + (size_t)(b * G_ + g) * 5;
    const float gxc = yrow[0], gyc = yrow[1], gw = yrow[2], gh = yrow[3];
    const int label = (int)yrow[4];
    const float gx2 = gxc + gw, gy2 = gyc + gh, garea = gw * gh;

    float best_iou = -1e30f;
    int best_idx = 0x7fffffff;
    float neg_sum = 0.0f, neg_cnt = 0.0f;

    // anchors floor(a/sf)*sf:
    // s0 sf=32: aw {96,128,352} ah {64,192,320}
    // s1 sf=16: aw {16, 48, 48} ah {48, 32,112}
    // s2 sf= 8: aw { 8, 16, 32} ah { 8, 24, 16}
    scan_scale<13, 0>(x0, b, 32.0f, 96.0f, 128.0f, 352.0f, 64.0f, 192.0f, 320.0f,
                      gxc, gyc, gx2, gy2, garea, best_iou, best_idx, neg_sum, neg_cnt);
    scan_scale<26, 507>(x1, b, 16.0f, 16.0f, 48.0f, 48.0f, 48.0f, 32.0f, 112.0f,
                        gxc, gyc, gx2, gy2, garea, best_iou, best_idx, neg_sum, neg_cnt);
    scan_scale<52, 2535>(x2, b, 8.0f, 8.0f, 16.0f, 32.0f, 8.0f, 24.0f, 16.0f,
                         gxc, gyc, gx2, gy2, garea, best_iou, best_idx, neg_sum, neg_cnt);

    // wave (64-lane) reduction: argmax with min-index tie-break + sums
    for (int off = 32; off > 0; off >>= 1) {
        float oi  = __shfl_down(best_iou, off);
        int   oix = __shfl_down(best_idx, off);
        float ons = __shfl_down(neg_sum, off);
        float onc = __shfl_down(neg_cnt, off);
        if (oi > best_iou || (oi == best_iou && oix < best_idx)) { best_iou = oi; best_idx = oix; }
        neg_sum += ons;
        neg_cnt += onc;
    }

    __shared__ float s_iou[4];
    __shared__ int   s_idx[4];
    __shared__ float s_ns[4], s_nc[4];
    const int wave = threadIdx.x >> 6;
    const int lane = threadIdx.x & 63;
    if (lane == 0) { s_iou[wave] = best_iou; s_idx[wave] = best_idx; s_ns[wave] = neg_sum; s_nc[wave] = neg_cnt; }
    __syncthreads();

    if (threadIdx.x < 64) {
        float biou = (lane < 4) ? s_iou[lane] : -1e30f;
        int   bidx = (lane < 4) ? s_idx[lane] : 0x7fffffff;
        float ns   = (lane < 4) ? s_ns[lane] : 0.0f;
        float nc   = (lane < 4) ? s_nc[lane] : 0.0f;
        for (int off = 2; off > 0; off >>= 1) {
            float oi  = __shfl_xor(biou, off);
            int   oix = __shfl_xor(bidx, off);
            float ons = __shfl_xor(ns, off);
            float onc = __shfl_xor(nc, off);
            if (oi > biou || (oi == biou && oix < bidx)) { biou = oi; bidx = oix; }
            ns += ons;
            nc += onc;
        }
        const int pos = __shfl(bidx, 0);  // broadcast winner to all 64 lanes

        // reverse map pos -> (scale ptr, anchor, spatial offset)
        const float* xp;
        int local, WWv;
        if (pos < 507)        { xp = x0; local = pos;        WWv = 169;  }
        else if (pos < 2535)  { xp = x1; local = pos - 507;  WWv = 676;  }
        else                  { xp = x2; local = pos - 2535; WWv = 2704; }
        const int a   = local / WWv;       // once per block: runtime div OK
        const int rem = local - a * WWv;
        const float* basep = xp + (size_t)(b * 255 + a * 85) * WWv + rem;

        // 80-class log-softmax over sigmoid(raw cls), parallel across wave 0
        float s0v = sigm(basep[(5 + lane) * WWv]);              // classes 0..63
        float s1v = -1e30f;
        if (lane < C_ - 64) s1v = sigm(basep[(5 + 64 + lane) * WWv]);  // classes 64..79
        float m = fmaxf(s0v, s1v);
        for (int off = 32; off > 0; off >>= 1) m = fmaxf(m, __shfl_xor(m, off));
        float e = expf(s0v - m) + ((lane < C_ - 64) ? expf(s1v - m) : 0.0f);
        for (int off = 32; off > 0; off >>= 1) e += __shfl_xor(e, off);

        if (lane == 0) {
            float vl = sigm(basep[(5 + label) * WWv]);
            float ce = -(vl - m - logf(e));  // -log_softmax at label

            float r0 = basep[0];
            float r1 = basep[WWv];
            float r2 = basep[2 * WWv];
            float r3 = basep[3 * WWv];
            float d0 = r0 - gxc, d1 = r1 - gyc, d2 = r2 - gw, d3 = r3 - gh;
            float mse = 0.25f * (d0 * d0 + d1 * d1 + d2 * d2 + d3 * d3);

            float confp = sigm(basep[4 * WWv]);
            float obj = logf(confp + 1e-9f);
            float noobj = ns / fmaxf(nc, 1.0f);

            atomicAdd(out, mse - obj - noobj - ce);
        }
    }
}

extern "C" void kernel_launch(void* const* d_in, const int* in_sizes, int n_in,
                              void* d_out, int out_size, void* d_ws, size_t ws_size,
                              hipStream_t stream) {
    const float* x0 = (const float*)d_in[0];
    const float* x1 = (const float*)d_in[1];
    const float* x2 = (const float*)d_in[2];
    const float* by = (const float*)d_in[3];
    float* out = (float*)d_out;

    hipLaunchKernelGGL(zero_out_kernel, dim3(1), dim3(1), 0, stream, out);
    dim3 grid(G_, B_);
    hipLaunchKernelGGL(yolo_loss_kernel, grid, dim3(256), 0, stream,
                       x0, x1, x2, by, out);
}

// Round 2
// 164.877 us; speedup vs baseline: 1.1002x; 1.1002x over previous
//
#include <hip/hip_runtime.h>

// YOLO loss forward, MI355X — two-phase.
// Phase A: decode each of 32*10647 preds ONCE (kills the 20x redundant
//          sigmoid/exp/log work that made R1 VALU-bound at 60us).
// Phase B: per-(b,g) IoU scan over decoded float8 records + fused epilogue.
// neg-mask sum via complement: neg_sum = tot_log1m[b] - sum_{iou>=0.5} log1m.

constexpr int B_ = 32;
constexpr int G_ = 20;
constexpr int C_ = 80;
constexpr int N_ = 10647;   // 507 + 2028 + 8112

constexpr size_t DEC_BYTES = (size_t)B_ * N_ * 2 * sizeof(float4); // 10,902,528
constexpr size_t WS_NEEDED = DEC_BYTES + B_ * sizeof(float);

__device__ __forceinline__ float sigm(float x) { return 1.0f / (1.0f + expf(-x)); }

// ---------------------------------------------------------------- init
__global__ void init_kernel(float* __restrict__ tot, float* __restrict__ out) {
    int t = threadIdx.x;
    if (t < B_) tot[t] = 0.0f;
    if (t == 0) out[0] = 0.0f;
}

// ---------------------------------------------------------------- phase A
// aw/ah args are floor(anchor/sf)*sf (exact: sf is a power of two).
template <int W, int NBASE>
__device__ __forceinline__ void decode_scale(
    const float* __restrict__ x, int b, int n, float sf,
    float aw0, float aw1, float aw2, float ah0, float ah1, float ah2,
    float4& d0, float4& d1)
{
    constexpr int WW = W * W;
    int local = n - NBASE;
    int a   = local / WW;          // magic-mul (WW constexpr)
    int rem = local - a * WW;
    int y   = rem / W;
    int xi  = rem - y * W;
    const float* base = x + (size_t)(b * 255 + a * 85) * WW + rem;
    float p0 = base[0];
    float p1 = base[WW];
    float p2 = base[2 * WW];
    float p3 = base[3 * WW];
    float p4 = base[4 * WW];
    float aw = (a == 0) ? aw0 : ((a == 1) ? aw1 : aw2);
    float ah = (a == 0) ? ah0 : ((a == 1) ? ah1 : ah2);
    float px = (sigm(p0) + (float)xi) * sf;
    float py = (sigm(p1) + (float)y) * sf;
    float pw = expf(p2) * aw;
    float ph = expf(p3) * ah;
    float conf  = sigm(p4);
    float log1m = logf(1.0f - conf + 1e-9f);
    d0 = make_float4(px, py, px + pw, py + ph);
    d1 = make_float4(pw * ph, log1m, 0.0f, 0.0f);
}

__global__ __launch_bounds__(256) void decode_kernel(
    const float* __restrict__ x0, const float* __restrict__ x1,
    const float* __restrict__ x2,
    float4* __restrict__ dec, float* __restrict__ tot)
{
    const int b = blockIdx.y;
    const int base = blockIdx.x * 1024;
    float lsum = 0.0f;
    for (int k = 0; k < 4; ++k) {
        int n = base + k * 256 + threadIdx.x;
        if (n < N_) {
            float4 d0, d1;
            if (n < 507)
                decode_scale<13, 0>(x0, b, n, 32.0f, 96.0f, 128.0f, 352.0f,
                                    64.0f, 192.0f, 320.0f, d0, d1);
            else if (n < 2535)
                decode_scale<26, 507>(x1, b, n, 16.0f, 16.0f, 48.0f, 48.0f,
                                      48.0f, 32.0f, 112.0f, d0, d1);
            else
                decode_scale<52, 2535>(x2, b, n, 8.0f, 8.0f, 16.0f, 32.0f,
                                       8.0f, 24.0f, 16.0f, d0, d1);
            lsum += d1.y;
            size_t o = ((size_t)b * N_ + n) * 2;
            dec[o]     = d0;
            dec[o + 1] = d1;
        }
    }
    // block-reduce lsum -> one atomicAdd per block
    for (int off = 32; off > 0; off >>= 1) lsum += __shfl_down(lsum, off);
    __shared__ float s_sum[4];
    const int wave = threadIdx.x >> 6;
    const int lane = threadIdx.x & 63;
    if (lane == 0) s_sum[wave] = lsum;
    __syncthreads();
    if (threadIdx.x == 0)
        atomicAdd(&tot[b], s_sum[0] + s_sum[1] + s_sum[2] + s_sum[3]);
}

// ---------------------------------------------------------------- phase B
__global__ __launch_bounds__(256) void scan_kernel(
    const float* __restrict__ x0, const float* __restrict__ x1,
    const float* __restrict__ x2,
    const float4* __restrict__ dec, const float* __restrict__ by,
    const float* __restrict__ tot, float* __restrict__ out)
{
    // XCD-aware mapping: blocks on XCD j (heuristic id%8) handle batches
    // 4j..4j+3 so each XCD's decoded working set (~1.4 MB) stays in its L2.
    const int id   = blockIdx.x;
    const int xcd  = id & 7;
    const int slot = id >> 3;            // 0..79
    const int q    = slot / 20;
    const int b    = xcd * 4 + q;
    const int g    = slot - q * 20;

    const float* yrow = by + (size_t)(b * G_ + g) * 5;
    const float gxc = yrow[0], gyc = yrow[1], gw = yrow[2], gh = yrow[3];
    const int label = (int)yrow[4];
    const float gx2 = gxc + gw, gy2 = gyc + gh, garea = gw * gh;

    const float4* dp = dec + (size_t)b * N_ * 2;

    float best_iou = -1.0f;
    int best_idx = 0x7fffffff;
    float pos_sum = 0.0f, pos_cnt = 0.0f;

    for (int n = threadIdx.x; n < N_; n += 256) {
        float4 d0 = dp[2 * n];
        float4 d1 = dp[2 * n + 1];
        float xl = fmaxf(d0.x, gxc);
        float yt = fmaxf(d0.y, gyc);
        float xr = fminf(d0.z, gx2);
        float yb = fminf(d0.w, gy2);
        float inter = fmaxf(xr - xl, 0.0f) * fmaxf(yb - yt, 0.0f);
        float u = d1.x + garea - inter;
        float iou = inter / u;                     // IEEE div: bit-match ref
        if (iou > best_iou) { best_iou = iou; best_idx = n; }
        if (iou >= 0.5f) { pos_sum += d1.y; pos_cnt += 1.0f; }
    }

    // wave reduction: argmax (min-index tie-break) + pos sums
    for (int off = 32; off > 0; off >>= 1) {
        float oi  = __shfl_down(best_iou, off);
        int   oix = __shfl_down(best_idx, off);
        float ops = __shfl_down(pos_sum, off);
        float opc = __shfl_down(pos_cnt, off);
        if (oi > best_iou || (oi == best_iou && oix < best_idx)) { best_iou = oi; best_idx = oix; }
        pos_sum += ops;
        pos_cnt += opc;
    }

    __shared__ float s_iou[4];
    __shared__ int   s_idx[4];
    __shared__ float s_ps[4], s_pc[4];
    const int wave = threadIdx.x >> 6;
    const int lane = threadIdx.x & 63;
    if (lane == 0) { s_iou[wave] = best_iou; s_idx[wave] = best_idx; s_ps[wave] = pos_sum; s_pc[wave] = pos_cnt; }
    __syncthreads();

    if (threadIdx.x < 64) {
        float biou = (lane < 4) ? s_iou[lane] : -1.0f;
        int   bidx = (lane < 4) ? s_idx[lane] : 0x7fffffff;
        float ps   = (lane < 4) ? s_ps[lane] : 0.0f;
        float pc   = (lane < 4) ? s_pc[lane] : 0.0f;
        for (int off = 2; off > 0; off >>= 1) {
            float oi  = __shfl_xor(biou, off);
            int   oix = __shfl_xor(bidx, off);
            float ops = __shfl_xor(ps, off);
            float opc = __shfl_xor(pc, off);
            if (oi > biou || (oi == biou && oix < bidx)) { biou = oi; bidx = oix; }
            ps += ops;
            pc += opc;
        }
        const int pos = __shfl(bidx, 0);   // broadcast winner

        // reverse map pos -> (scale ptr, anchor, spatial offset)
        const float* xp;
        int local, WWv;
        if (pos < 507)        { xp = x0; local = pos;        WWv = 169;  }
        else if (pos < 2535)  { xp = x1; local = pos - 507;  WWv = 676;  }
        else                  { xp = x2; local = pos - 2535; WWv = 2704; }
        const int a   = local / WWv;
        const int rem = local - a * WWv;
        const float* basep = xp + (size_t)(b * 255 + a * 85) * WWv + rem;

        // 80-class log-softmax over sigmoid(raw cls), parallel across wave 0
        float s0v = sigm(basep[(5 + lane) * WWv]);
        float s1v = -1e30f;
        if (lane < C_ - 64) s1v = sigm(basep[(5 + 64 + lane) * WWv]);
        float m = fmaxf(s0v, s1v);
        for (int off = 32; off > 0; off >>= 1) m = fmaxf(m, __shfl_xor(m, off));
        float e = expf(s0v - m) + ((lane < C_ - 64) ? expf(s1v - m) : 0.0f);
        for (int off = 32; off > 0; off >>= 1) e += __shfl_xor(e, off);

        if (lane == 0) {
            float vl = sigm(basep[(5 + label) * WWv]);
            float ce = -(vl - m - logf(e));

            float r0 = basep[0];
            float r1 = basep[WWv];
            float r2 = basep[2 * WWv];
            float r3 = basep[3 * WWv];
            float d0 = r0 - gxc, d1 = r1 - gyc, d2 = r2 - gw, d3 = r3 - gh;
            float mse = 0.25f * (d0 * d0 + d1 * d1 + d2 * d2 + d3 * d3);

            float confp = sigm(basep[4 * WWv]);
            float obj = logf(confp + 1e-9f);

            float neg_sum = tot[b] - ps;
            float neg_cnt = (float)N_ - pc;
            float noobj = neg_sum / fmaxf(neg_cnt, 1.0f);

            atomicAdd(out, mse - obj - noobj - ce);
        }
    }
}

// ---------------------------------------------------------------- fallback
// (R1 single-kernel path, used only if ws_size is too small)
__global__ void zero_out_kernel(float* __restrict__ out) { out[0] = 0.0f; }

template <int W, int NBASE>
__device__ __forceinline__ void scan_scale_fb(
    const float* __restrict__ x, int b, float sf,
    float aw0, float aw1, float aw2, float ah0, float ah1, float ah2,
    float gxc, float gyc, float gx2, float gy2, float garea,
    float& best_iou, int& best_idx, float& neg_sum, float& neg_cnt)
{
    constexpr int WW = W * W;
    constexpr int NS = 3 * WW;
    for (int i = threadIdx.x; i < NS; i += 256) {
        int a   = i / WW;
        int rem = i - a * WW;
        int y   = rem / W;
        int xi  = rem - y * W;
        const float* base = x + (size_t)(b * 255 + a * 85) * WW + rem;
        float p0 = base[0], p1 = base[WW], p2 = base[2 * WW], p3 = base[3 * WW], p4 = base[4 * WW];
        float aw = (a == 0) ? aw0 : ((a == 1) ? aw1 : aw2);
        float ah = (a == 0) ? ah0 : ((a == 1) ? ah1 : ah2);
        float px = (sigm(p0) + (float)xi) * sf;
        float py = (sigm(p1) + (float)y) * sf;
        float pw = expf(p2) * aw;
        float ph = expf(p3) * ah;
        float conf = sigm(p4);
        float xl = fmaxf(px, gxc), yt = fmaxf(py, gyc);
        float xr = fminf(px + pw, gx2), yb = fminf(py + ph, gy2);
        float inter = fmaxf(xr - xl, 0.0f) * fmaxf(yb - yt, 0.0f);
        float iou = inter / (pw * ph + garea - inter);
        if (iou > best_iou) { best_iou = iou; best_idx = NBASE + i; }
        if (iou < 0.5f) { neg_sum += logf(1.0f - conf + 1e-9f); neg_cnt += 1.0f; }
    }
}

__global__ __launch_bounds__(256) void yolo_loss_fallback(
    const float* __restrict__ x0, const float* __restrict__ x1,
    const float* __restrict__ x2, const float* __restrict__ by,
    float* __restrict__ out)
{
    const int g = blockIdx.x;
    const int b = blockIdx.y;
    const float* yrow = by + (size_t)(b * G_ + g) * 5;
    const float gxc = yrow[0], gyc = yrow[1], gw = yrow[2], gh = yrow[3];
    const int label = (int)yrow[4];
    const float gx2 = gxc + gw, gy2 = gyc + gh, garea = gw * gh;

    float best_iou = -1e30f;
    int best_idx = 0x7fffffff;
    float neg_sum = 0.0f, neg_cnt = 0.0f;

    scan_scale_fb<13, 0>(x0, b, 32.0f, 96.0f, 128.0f, 352.0f, 64.0f, 192.0f, 320.0f,
                         gxc, gyc, gx2, gy2, garea, best_iou, best_idx, neg_sum, neg_cnt);
    scan_scale_fb<26, 507>(x1, b, 16.0f, 16.0f, 48.0f, 48.0f, 48.0f, 32.0f, 112.0f,
                           gxc, gyc, gx2, gy2, garea, best_iou, best_idx, neg_sum, neg_cnt);
    scan_scale_fb<52, 2535>(x2, b, 8.0f, 8.0f, 16.0f, 32.0f, 8.0f, 24.0f, 16.0f,
                            gxc, gyc, gx2, gy2, garea, best_iou, best_idx, neg_sum, neg_cnt);

    for (int off = 32; off > 0; off >>= 1) {
        float oi  = __shfl_down(best_iou, off);
        int   oix = __shfl_down(best_idx, off);
        float ons = __shfl_down(neg_sum, off);
        float onc = __shfl_down(neg_cnt, off);
        if (oi > best_iou || (oi == best_iou && oix < best_idx)) { best_iou = oi; best_idx = oix; }
        neg_sum += ons;
        neg_cnt += onc;
    }

    __shared__ float s_iou[4];
    __shared__ int   s_idx[4];
    __shared__ float s_ns[4], s_nc[4];
    const int wave = threadIdx.x >> 6;
    const int lane = threadIdx.x & 63;
    if (lane == 0) { s_iou[wave] = best_iou; s_idx[wave] = best_idx; s_ns[wave] = neg_sum; s_nc[wave] = neg_cnt; }
    __syncthreads();

    if (threadIdx.x < 64) {
        float biou = (lane < 4) ? s_iou[lane] : -1e30f;
        int   bidx = (lane < 4) ? s_idx[lane] : 0x7fffffff;
        float ns   = (lane < 4) ? s_ns[lane] : 0.0f;
        float nc   = (lane < 4) ? s_nc[lane] : 0.0f;
        for (int off = 2; off > 0; off >>= 1) {
            float oi  = __shfl_xor(biou, off);
            int   oix = __shfl_xor(bidx, off);
            float ons = __shfl_xor(ns, off);
            float onc = __shfl_xor(nc, off);
            if (oi > biou || (oi == biou && oix < bidx)) { biou = oi; bidx = oix; }
            ns += ons;
            nc += onc;
        }
        const int pos = __shfl(bidx, 0);

        const float* xp;
        int local, WWv;
        if (pos < 507)        { xp = x0; local = pos;        WWv = 169;  }
        else if (pos < 2535)  { xp = x1; local = pos - 507;  WWv = 676;  }
        else                  { xp = x2; local = pos - 2535; WWv = 2704; }
        const int a   = local / WWv;
        const int rem = local - a * WWv;
        const float* basep = xp + (size_t)(b * 255 + a * 85) * WWv + rem;

        float s0v = sigm(basep[(5 + lane) * WWv]);
        float s1v = -1e30f;
        if (lane < C_ - 64) s1v = sigm(basep[(5 + 64 + lane) * WWv]);
        float m = fmaxf(s0v, s1v);
        for (int off = 32; off > 0; off >>= 1) m = fmaxf(m, __shfl_xor(m, off));
        float e = expf(s0v - m) + ((lane < C_ - 64) ? expf(s1v - m) : 0.0f);
        for (int off = 32; off > 0; off >>= 1) e += __shfl_xor(e, off);

        if (lane == 0) {
            float vl = sigm(basep[(5 + label) * WWv]);
            float ce = -(vl - m - logf(e));
            float r0 = basep[0], r1 = basep[WWv], r2 = basep[2 * WWv], r3 = basep[3 * WWv];
            float d0 = r0 - gxc, d1 = r1 - gyc, d2 = r2 - gw, d3 = r3 - gh;
            float mse = 0.25f * (d0 * d0 + d1 * d1 + d2 * d2 + d3 * d3);
            float confp = sigm(basep[4 * WWv]);
            float obj = logf(confp + 1e-9f);
            float noobj = ns / fmaxf(nc, 1.0f);
            atomicAdd(out, mse - obj - noobj - ce);
        }
    }
}

// ---------------------------------------------------------------- launch
extern "C" void kernel_launch(void* const* d_in, const int* in_sizes, int n_in,
                              void* d_out, int out_size, void* d_ws, size_t ws_size,
                              hipStream_t stream) {
    const float* x0 = (const float*)d_in[0];
    const float* x1 = (const float*)d_in[1];
    const float* x2 = (const float*)d_in[2];
    const float* by = (const float*)d_in[3];
    float* out = (float*)d_out;

    if (ws_size >= WS_NEEDED) {
        float4* dec = (float4*)d_ws;
        float*  tot = (float*)((char*)d_ws + DEC_BYTES);
        hipLaunchKernelGGL(init_kernel, dim3(1), dim3(64), 0, stream, tot, out);
        hipLaunchKernelGGL(decode_kernel, dim3(11, B_), dim3(256), 0, stream,
                           x0, x1, x2, dec, tot);
        hipLaunchKernelGGL(scan_kernel, dim3(B_ * G_), dim3(256), 0, stream,
                           x0, x1, x2, dec, by, tot, out);
    } else {
        hipLaunchKernelGGL(zero_out_kernel, dim3(1), dim3(1), 0, stream, out);
        hipLaunchKernelGGL(yolo_loss_fallback, dim3(G_, B_), dim3(256), 0, stream,
                           x0, x1, x2, by, out);
    }
}